// Round 6
// baseline (258.187 us; speedup 1.0000x reference)
//
#include <hip/hip_runtime.h>

#define N_NODES 50000
#define N_EDGES 800000
#define PAD_N   51200          // >= 49*1024, zero-padded tail
#define SCAN_BLOCKS 49         // 49 * 1024 = 50176 >= N_NODES+1

// ---- bf16 helpers (manual RNE; avoids header type juggling) ----------------
__device__ __forceinline__ unsigned short f2bf(float f) {
    union { float f; unsigned u; } v; v.f = f;
    unsigned r = v.u + 0x7fffu + ((v.u >> 16) & 1u);
    return (unsigned short)(r >> 16);
}
__device__ __forceinline__ float bflo(unsigned u) {   // low bf16 of a packed pair
    union { unsigned u; float f; } v; v.u = u << 16; return v.f;
}
__device__ __forceinline__ float bfhi(unsigned u) {   // high bf16 of a packed pair
    union { unsigned u; float f; } v; v.u = u & 0xffff0000u; return v.f;
}

// ---------------------------------------------------------------------------
// Fused: histogram of dst (int4, L2-resident atomics) + cast x -> bf16.
// Grid sized for the cast (3125 blocks); hist uses the first 200000 threads.
// ---------------------------------------------------------------------------
__global__ void hist_cast_kernel(const int* __restrict__ dst,
                                 const float* __restrict__ x,
                                 int* __restrict__ cnt,
                                 unsigned short* __restrict__ xbf) {
    const int tid = blockIdx.x * 256 + threadIdx.x;      // < 800000
    {   // cast 4 floats -> 4 bf16
        float4 v = *(const float4*)(x + tid * 4);
        ushort4 o = { f2bf(v.x), f2bf(v.y), f2bf(v.z), f2bf(v.w) };
        *(ushort4*)(xbf + tid * 4) = o;
    }
    if (tid < N_EDGES / 4) {
        int4 d = *(const int4*)(dst + tid * 4);
        atomicAdd(&cnt[d.x], 1);
        atomicAdd(&cnt[d.y], 1);
        atomicAdd(&cnt[d.z], 1);
        atomicAdd(&cnt[d.w], 1);
    }
}

// ---------------------------------------------------------------------------
// Scan step A: per-block (1024-elem chunk) local exclusive scan + block sum.
// ---------------------------------------------------------------------------
__global__ void scanA_kernel(const int* __restrict__ cnt,
                             int* __restrict__ loc,
                             int* __restrict__ bsum) {
    __shared__ int lds[256];
    const int b = blockIdx.x, t = threadIdx.x;
    const int base = b * 1024 + t * 4;
    int4 v = *(const int4*)(cnt + base);
    const int s = v.x + v.y + v.z + v.w;
    lds[t] = s;
    __syncthreads();
    for (int off = 1; off < 256; off <<= 1) {
        int u = (t >= off) ? lds[t - off] : 0;
        __syncthreads();
        lds[t] += u;
        __syncthreads();
    }
    const int excl = lds[t] - s;
    int4 o;
    o.x = excl;
    o.y = excl + v.x;
    o.z = excl + v.x + v.y;
    o.w = excl + v.x + v.y + v.z;
    *(int4*)(loc + base) = o;
    if (t == 255) bsum[b] = lds[255];
}

// ---------------------------------------------------------------------------
// Scan step C (scanB fused): every wave shfl-scans the 49 block sums itself,
// then adds the offset and emits rowptr + cursor (int4 coalesced).
// rowptr[N_NODES] = 800000 falls out of the zero padding.
// ---------------------------------------------------------------------------
__global__ void scanC_kernel(const int* __restrict__ loc,
                             const int* __restrict__ bsum,
                             int* __restrict__ rowptr,
                             int* __restrict__ cursor) {
    const int b = blockIdx.x, t = threadIdx.x;
    const int lane = t & 63;
    int v = (lane < SCAN_BLOCKS) ? bsum[lane] : 0;
    for (int off = 1; off < 64; off <<= 1) {
        int u = __shfl_up(v, off);
        if (lane >= off) v += u;
    }
    const int boff = (b == 0) ? 0 : __shfl(v, b - 1);    // exclusive offset
    const int base = b * 1024 + t * 4;
    int4 w = *(const int4*)(loc + base);
    w.x += boff; w.y += boff; w.z += boff; w.w += boff;
    *(int4*)(rowptr + base) = w;
    *(int4*)(cursor + base) = w;
}

// ---------------------------------------------------------------------------
// CSR fill: place each edge's src into its dst segment (int4 edge loads).
// ---------------------------------------------------------------------------
__global__ void fill_kernel(const int* __restrict__ src,
                            const int* __restrict__ dst,
                            int* __restrict__ cursor,
                            int* __restrict__ csr_src) {
    const int e4 = blockIdx.x * 256 + threadIdx.x;
    if (e4 >= N_EDGES / 4) return;
    int4 s = *(const int4*)(src + e4 * 4);
    int4 d = *(const int4*)(dst + e4 * 4);
    csr_src[atomicAdd(&cursor[d.x], 1)] = s.x;
    csr_src[atomicAdd(&cursor[d.y], 1)] = s.y;
    csr_src[atomicAdd(&cursor[d.z], 1)] = s.z;
    csr_src[atomicAdd(&cursor[d.w], 1)] = s.w;
}

// ---------------------------------------------------------------------------
// Fused layer 1. One wave per node. Lane: c = l&7 (8-feature chunk),
// g = l>>3 (group 0..7). Gather: xbf row = exactly one 128B line; one
// wave-load = 8 distinct rows; unroll x2 -> 16 rows in flight. Neighbor
// slots are contiguous per group so index loads are adjacent.
// Matmul k-range split 8 ways; h stays in registers; y2 (bf16) and
// z = h@W2_r + b2 (fp32) are the only outputs.
// NOTE (R5 bug): any __shfl value expression must be lane-uniform in its
// indexing — divergent selection (hi ? a : b) must happen AFTER the shuffle.
// ---------------------------------------------------------------------------
__global__ __launch_bounds__(256) void layer1_kernel(
        const float* __restrict__ x,
        const unsigned short* __restrict__ xbf,
        const int* __restrict__ rowptr,
        const int* __restrict__ csr_src,
        const float* __restrict__ W1_l,
        const float* __restrict__ b1,
        const float* __restrict__ W1_r,
        const float* __restrict__ W2_l,
        const float* __restrict__ W2_r,
        const float* __restrict__ b2,
        unsigned short* __restrict__ y2,
        float* __restrict__ z) {
    const int n = blockIdx.x * 4 + (threadIdx.x >> 6);
    const int l = threadIdx.x & 63;
    const int c = l & 7;
    const int g = l >> 3;

    const int beg = rowptr[n];
    const int end = rowptr[n + 1];
    const int deg = end - beg;
    const int chunk = (deg + 7) >> 3;

    // ---- gather-mean over this group's contiguous neighbor chunk ----
    float s[8] = {0.f, 0.f, 0.f, 0.f, 0.f, 0.f, 0.f, 0.f};
    {
        int i = beg + g * chunk;
        const int ce = min(i + chunk, end);
        for (; i + 1 < ce; i += 2) {
            const int a = csr_src[i];
            const int b = csr_src[i + 1];
            uint4 ua = *(const uint4*)(xbf + a * 64 + c * 8);
            uint4 ub = *(const uint4*)(xbf + b * 64 + c * 8);
            s[0] += bflo(ua.x) + bflo(ub.x); s[1] += bfhi(ua.x) + bfhi(ub.x);
            s[2] += bflo(ua.y) + bflo(ub.y); s[3] += bfhi(ua.y) + bfhi(ub.y);
            s[4] += bflo(ua.z) + bflo(ub.z); s[5] += bfhi(ua.z) + bfhi(ub.z);
            s[6] += bflo(ua.w) + bflo(ub.w); s[7] += bfhi(ua.w) + bfhi(ub.w);
        }
        if (i < ce) {
            const int a = csr_src[i];
            uint4 ua = *(const uint4*)(xbf + a * 64 + c * 8);
            s[0] += bflo(ua.x); s[1] += bfhi(ua.x);
            s[2] += bflo(ua.y); s[3] += bfhi(ua.y);
            s[4] += bflo(ua.z); s[5] += bfhi(ua.z);
            s[6] += bflo(ua.w); s[7] += bfhi(ua.w);
        }
    }
    #pragma unroll
    for (int e = 0; e < 8; ++e) {
        s[e] += __shfl_xor(s[e], 8);
        s[e] += __shfl_xor(s[e], 16);
        s[e] += __shfl_xor(s[e], 32);
    }
    const float rdeg = 1.0f / fmaxf((float)deg, 1.0f);
    float m[8], xs[8];
    #pragma unroll
    for (int e = 0; e < 8; ++e) m[e] = s[e] * rdeg;
    {   // self row, fp32-exact
        float4 x0 = *(const float4*)(x + n * 64 + c * 8);
        float4 x1 = *(const float4*)(x + n * 64 + c * 8 + 4);
        xs[0] = x0.x; xs[1] = x0.y; xs[2] = x0.z; xs[3] = x0.w;
        xs[4] = x1.x; xs[5] = x1.y; xs[6] = x1.z; xs[7] = x1.w;
    }

    // ---- acc = mean@W1_l + x@W1_r; k in [8g, 8g+8) per group ----
    float acc[8] = {0.f, 0.f, 0.f, 0.f, 0.f, 0.f, 0.f, 0.f};
    #pragma unroll
    for (int kk = 0; kk < 8; ++kk) {
        const int k = 8 * g + kk;
        const float mk = __shfl(m[kk], g);       // lane g holds chunk g; kk uniform
        const float xk = __shfl(xs[kk], g);
        const float4 wl0 = *(const float4*)(W1_l + k * 64 + c * 8);
        const float4 wl1 = *(const float4*)(W1_l + k * 64 + c * 8 + 4);
        const float4 wr0 = *(const float4*)(W1_r + k * 64 + c * 8);
        const float4 wr1 = *(const float4*)(W1_r + k * 64 + c * 8 + 4);
        acc[0] = fmaf(mk, wl0.x, acc[0]); acc[0] = fmaf(xk, wr0.x, acc[0]);
        acc[1] = fmaf(mk, wl0.y, acc[1]); acc[1] = fmaf(xk, wr0.y, acc[1]);
        acc[2] = fmaf(mk, wl0.z, acc[2]); acc[2] = fmaf(xk, wr0.z, acc[2]);
        acc[3] = fmaf(mk, wl0.w, acc[3]); acc[3] = fmaf(xk, wr0.w, acc[3]);
        acc[4] = fmaf(mk, wl1.x, acc[4]); acc[4] = fmaf(xk, wr1.x, acc[4]);
        acc[5] = fmaf(mk, wl1.y, acc[5]); acc[5] = fmaf(xk, wr1.y, acc[5]);
        acc[6] = fmaf(mk, wl1.z, acc[6]); acc[6] = fmaf(xk, wr1.z, acc[6]);
        acc[7] = fmaf(mk, wl1.w, acc[7]); acc[7] = fmaf(xk, wr1.w, acc[7]);
    }
    #pragma unroll
    for (int e = 0; e < 8; ++e) {
        acc[e] += __shfl_xor(acc[e], 8);
        acc[e] += __shfl_xor(acc[e], 16);
        acc[e] += __shfl_xor(acc[e], 32);
    }
    float h[8];
    {
        float4 bb0 = *(const float4*)(b1 + c * 8);
        float4 bb1 = *(const float4*)(b1 + c * 8 + 4);
        h[0] = fmaxf(acc[0] + bb0.x, 0.f); h[1] = fmaxf(acc[1] + bb0.y, 0.f);
        h[2] = fmaxf(acc[2] + bb0.z, 0.f); h[3] = fmaxf(acc[3] + bb0.w, 0.f);
        h[4] = fmaxf(acc[4] + bb1.x, 0.f); h[5] = fmaxf(acc[5] + bb1.y, 0.f);
        h[6] = fmaxf(acc[6] + bb1.z, 0.f); h[7] = fmaxf(acc[7] + bb1.w, 0.f);
    }

    // ---- y2 = h@W2_l (bf16 out), z = h@W2_r + b2 (fp32) ----
    // lane: oc = l&3 (4 outputs), seg = l>>2 (k in [4seg,4seg+4))
    const int oc = l & 3;
    const int seg = l >> 2;
    const int hs = seg >> 1;            // source lane holding chunk seg>>1
    const bool hi = (seg & 1);          // upper half of that lane's h[8]
    float p[4] = {0.f, 0.f, 0.f, 0.f};
    float q[4] = {0.f, 0.f, 0.f, 0.f};
    #pragma unroll
    for (int t2 = 0; t2 < 4; ++t2) {
        const int k = 4 * seg + t2;
        // R5 FIX: shuffle both halves (uniform index), select AFTER the shuffle
        const float hlo = __shfl(h[t2], hs);
        const float hhi = __shfl(h[4 + t2], hs);
        const float hk = hi ? hhi : hlo;
        const float4 w2l = *(const float4*)(W2_l + k * 16 + 4 * oc);
        const float4 w2r = *(const float4*)(W2_r + k * 16 + 4 * oc);
        p[0] = fmaf(hk, w2l.x, p[0]); q[0] = fmaf(hk, w2r.x, q[0]);
        p[1] = fmaf(hk, w2l.y, p[1]); q[1] = fmaf(hk, w2r.y, q[1]);
        p[2] = fmaf(hk, w2l.z, p[2]); q[2] = fmaf(hk, w2r.z, q[2]);
        p[3] = fmaf(hk, w2l.w, p[3]); q[3] = fmaf(hk, w2r.w, q[3]);
    }
    #pragma unroll
    for (int e = 0; e < 4; ++e) {
        p[e] += __shfl_xor(p[e], 4);  p[e] += __shfl_xor(p[e], 8);
        p[e] += __shfl_xor(p[e], 16); p[e] += __shfl_xor(p[e], 32);
        q[e] += __shfl_xor(q[e], 4);  q[e] += __shfl_xor(q[e], 8);
        q[e] += __shfl_xor(q[e], 16); q[e] += __shfl_xor(q[e], 32);
    }
    if (l < 4) {   // oc == l, seg == 0
        ushort4 yb = { f2bf(p[0]), f2bf(p[1]), f2bf(p[2]), f2bf(p[3]) };
        *(ushort4*)(y2 + n * 16 + 4 * l) = yb;
        const float4 b2v = *(const float4*)(b2 + 4 * l);
        float4 z4 = { q[0] + b2v.x, q[1] + b2v.y, q[2] + b2v.z, q[3] + b2v.w };
        *(float4*)(z + n * 16 + 4 * l) = z4;
    }
}

// ---------------------------------------------------------------------------
// Fused layer 2: gather-mean of bf16 y2 (32B rows, 2 lanes/row, 8 slots/node,
// 4 nodes/wave) + z -> out.
// ---------------------------------------------------------------------------
__global__ __launch_bounds__(256) void layer2_kernel(
        const unsigned short* __restrict__ y2,
        const float* __restrict__ z,
        const int* __restrict__ rowptr,
        const int* __restrict__ csr_src,
        float* __restrict__ out) {
    const int wv = blockIdx.x * 4 + (threadIdx.x >> 6);
    const int l = threadIdx.x & 63;
    const int n = wv * 4 + (l >> 4);
    const int t = l & 15;
    const int c2 = t & 1;        // feature half (8 outputs)
    const int p2 = t >> 1;       // neighbor slot 0..7

    const int beg = rowptr[n];
    const int end = rowptr[n + 1];
    const int deg = end - beg;
    const int chunk = (deg + 7) >> 3;

    float s[8] = {0.f, 0.f, 0.f, 0.f, 0.f, 0.f, 0.f, 0.f};
    {
        int i = beg + p2 * chunk;
        const int ce = min(i + chunk, end);
        for (; i + 1 < ce; i += 2) {
            const int a = csr_src[i];
            const int b = csr_src[i + 1];
            uint4 ua = *(const uint4*)(y2 + a * 16 + c2 * 8);
            uint4 ub = *(const uint4*)(y2 + b * 16 + c2 * 8);
            s[0] += bflo(ua.x) + bflo(ub.x); s[1] += bfhi(ua.x) + bfhi(ub.x);
            s[2] += bflo(ua.y) + bflo(ub.y); s[3] += bfhi(ua.y) + bfhi(ub.y);
            s[4] += bflo(ua.z) + bflo(ub.z); s[5] += bfhi(ua.z) + bfhi(ub.z);
            s[6] += bflo(ua.w) + bflo(ub.w); s[7] += bfhi(ua.w) + bfhi(ub.w);
        }
        if (i < ce) {
            const int a = csr_src[i];
            uint4 ua = *(const uint4*)(y2 + a * 16 + c2 * 8);
            s[0] += bflo(ua.x); s[1] += bfhi(ua.x);
            s[2] += bflo(ua.y); s[3] += bfhi(ua.y);
            s[4] += bflo(ua.z); s[5] += bfhi(ua.z);
            s[6] += bflo(ua.w); s[7] += bfhi(ua.w);
        }
    }
    #pragma unroll
    for (int e = 0; e < 8; ++e) {
        s[e] += __shfl_xor(s[e], 2);
        s[e] += __shfl_xor(s[e], 4);
        s[e] += __shfl_xor(s[e], 8);
    }
    if (p2 == 0) {
        const float rdeg = 1.0f / fmaxf((float)deg, 1.0f);
        const float4 z0 = *(const float4*)(z + n * 16 + c2 * 8);
        const float4 z1 = *(const float4*)(z + n * 16 + c2 * 8 + 4);
        float4 o0 = { s[0] * rdeg + z0.x, s[1] * rdeg + z0.y,
                      s[2] * rdeg + z0.z, s[3] * rdeg + z0.w };
        float4 o1 = { s[4] * rdeg + z1.x, s[5] * rdeg + z1.y,
                      s[6] * rdeg + z1.z, s[7] * rdeg + z1.w };
        *(float4*)(out + n * 16 + c2 * 8) = o0;
        *(float4*)(out + n * 16 + c2 * 8 + 4) = o1;
    }
}

extern "C" void kernel_launch(void* const* d_in, const int* in_sizes, int n_in,
                              void* d_out, int out_size, void* d_ws, size_t ws_size,
                              hipStream_t stream) {
    const float* x    = (const float*)d_in[0];
    const int*   ei   = (const int*)d_in[1];   // [2, 800000]: row 0 = src, row 1 = dst
    const float* W1_l = (const float*)d_in[2];
    const float* b1   = (const float*)d_in[3];
    const float* W1_r = (const float*)d_in[4];
    const float* W2_l = (const float*)d_in[5];
    const float* b2   = (const float*)d_in[6];
    const float* W2_r = (const float*)d_in[7];
    float* out = (float*)d_out;

    const int* src = ei;
    const int* dst = ei + N_EDGES;

    // Workspace layout (4-byte units):
    int*   cnt     = (int*)d_ws;                    // PAD_N
    int*   loc     = cnt     + PAD_N;               // PAD_N
    int*   rowptr  = loc     + PAD_N;               // PAD_N
    int*   cursor  = rowptr  + PAD_N;               // PAD_N
    int*   bsum    = cursor  + PAD_N;               // 64
    int*   csr_src = bsum    + 64;                  // 800,000
    unsigned short* xbf = (unsigned short*)(csr_src + 800000);   // 3,200,000 u16
    unsigned short* y2  = xbf + 3200000;            // 800,000 u16
    float* z       = (float*)(y2 + 800000);         // 800,000 f32
    // total ~15.2 MB

    hipMemsetAsync(cnt, 0, PAD_N * sizeof(int), stream);

    hist_cast_kernel<<<3125, 256, 0, stream>>>(dst, x, cnt, xbf);
    scanA_kernel<<<SCAN_BLOCKS, 256, 0, stream>>>(cnt, loc, bsum);
    scanC_kernel<<<SCAN_BLOCKS, 256, 0, stream>>>(loc, bsum, rowptr, cursor);
    fill_kernel<<<(N_EDGES / 4 + 255) / 256, 256, 0, stream>>>(src, dst, cursor, csr_src);
    layer1_kernel<<<N_NODES / 4, 256, 0, stream>>>(x, xbf, rowptr, csr_src,
                                                   W1_l, b1, W1_r,
                                                   W2_l, W2_r, b2, y2, z);
    layer2_kernel<<<N_NODES / 16, 256, 0, stream>>>(y2, z, rowptr, csr_src, out);
}

// Round 7
// 202.824 us; speedup vs baseline: 1.2730x; 1.2730x over previous
//
#include <hip/hip_runtime.h>

#define N_NODES 50000
#define N_EDGES 800000
#define PAD_N   51200          // >= 49*1024, zero-padded tail
#define SCAN_BLOCKS 49         // 49 * 1024 = 50176 >= N_NODES+1

typedef _Float16 h2v __attribute__((ext_vector_type(2)));
typedef _Float16 h8v __attribute__((ext_vector_type(8)));
typedef float    f4v __attribute__((ext_vector_type(4)));

union H2U { h2v h; unsigned u; };   // packed f16 pair <-> dword

// ---------------------------------------------------------------------------
// Prep: histogram of dst + cast x -> f16 + pack W1/W2 into MFMA B-fragment
// order (block 0 only). B-frag layout for 16x16x32 f16: lane holds 8 f16
// B[k = 32*kt + (lane>>4)*8 + j][n = 16*nt + (lane&15)], stored so the MLP
// kernel loads one contiguous uint4 per (frag, lane).
// ---------------------------------------------------------------------------
__global__ void prep_kernel(const int* __restrict__ dst,
                            const float* __restrict__ x,
                            const float* __restrict__ W1_l,
                            const float* __restrict__ W1_r,
                            const float* __restrict__ W2_l,
                            const float* __restrict__ W2_r,
                            int* __restrict__ cnt,
                            _Float16* __restrict__ xf,
                            _Float16* __restrict__ B1,
                            _Float16* __restrict__ B2) {
    const int tid = blockIdx.x * 256 + threadIdx.x;      // < 800000
    {   // cast 4 floats -> 4 f16
        float4 v = *(const float4*)(x + tid * 4);
        H2U a, b;
        a.h = h2v{ (_Float16)v.x, (_Float16)v.y };
        b.h = h2v{ (_Float16)v.z, (_Float16)v.w };
        uint2 o = { a.u, b.u };
        *(uint2*)(xf + tid * 4) = o;
    }
    if (tid < N_EDGES / 4) {
        int4 d = *(const int4*)(dst + tid * 4);
        atomicAdd(&cnt[d.x], 1);
        atomicAdd(&cnt[d.y], 1);
        atomicAdd(&cnt[d.z], 1);
        atomicAdd(&cnt[d.w], 1);
    }
    if (blockIdx.x == 0) {
        const int t = threadIdx.x;
        // B1: [W1_l; W1_r] (128 x 64), 16 frags (kt 0..3, nt 0..3)
        for (int p = t; p < 16 * 512; p += 256) {
            const int frag = p >> 9, lane = (p >> 3) & 63, j = p & 7;
            const int kt = frag >> 2, nt = frag & 3;
            const int k = kt * 32 + (lane >> 4) * 8 + j;
            const int n = nt * 16 + (lane & 15);
            const float w = (k < 64) ? W1_l[k * 64 + n] : W1_r[(k - 64) * 64 + n];
            B1[p] = (_Float16)w;
        }
        // B2: [W2_l | W2_r] (64 x 32), 4 frags (kt 0..1, nt 0..1)
        for (int p = t; p < 4 * 512; p += 256) {
            const int frag = p >> 9, lane = (p >> 3) & 63, j = p & 7;
            const int kt = frag >> 1, nt = frag & 1;
            const int k = kt * 32 + (lane >> 4) * 8 + j;
            const int n = lane & 15;
            const float w = (nt == 0) ? W2_l[k * 16 + n] : W2_r[k * 16 + n];
            B2[p] = (_Float16)w;
        }
    }
}

// ---------------------------------------------------------------------------
// Scan step A: per-block (1024-elem chunk) local exclusive scan + block sum.
// ---------------------------------------------------------------------------
__global__ void scanA_kernel(const int* __restrict__ cnt,
                             int* __restrict__ loc,
                             int* __restrict__ bsum) {
    __shared__ int lds[256];
    const int b = blockIdx.x, t = threadIdx.x;
    const int base = b * 1024 + t * 4;
    int4 v = *(const int4*)(cnt + base);
    const int s = v.x + v.y + v.z + v.w;
    lds[t] = s;
    __syncthreads();
    for (int off = 1; off < 256; off <<= 1) {
        int u = (t >= off) ? lds[t - off] : 0;
        __syncthreads();
        lds[t] += u;
        __syncthreads();
    }
    const int excl = lds[t] - s;
    int4 o;
    o.x = excl;
    o.y = excl + v.x;
    o.z = excl + v.x + v.y;
    o.w = excl + v.x + v.y + v.z;
    *(int4*)(loc + base) = o;
    if (t == 255) bsum[b] = lds[255];
}

// ---------------------------------------------------------------------------
// Scan step C: every wave shfl-scans the 49 block sums, adds offset, emits
// rowptr + cursor. rowptr[N_NODES]=800000 falls out of the zero padding.
// ---------------------------------------------------------------------------
__global__ void scanC_kernel(const int* __restrict__ loc,
                             const int* __restrict__ bsum,
                             int* __restrict__ rowptr,
                             int* __restrict__ cursor) {
    const int b = blockIdx.x, t = threadIdx.x;
    const int lane = t & 63;
    int v = (lane < SCAN_BLOCKS) ? bsum[lane] : 0;
    for (int off = 1; off < 64; off <<= 1) {
        int u = __shfl_up(v, off);
        if (lane >= off) v += u;
    }
    const int boff = (b == 0) ? 0 : __shfl(v, b - 1);
    const int base = b * 1024 + t * 4;
    int4 w = *(const int4*)(loc + base);
    w.x += boff; w.y += boff; w.z += boff; w.w += boff;
    *(int4*)(rowptr + base) = w;
    *(int4*)(cursor + base) = w;
}

// ---------------------------------------------------------------------------
// CSR fill: place each edge's src into its dst segment (int4 edge loads).
// ---------------------------------------------------------------------------
__global__ void fill_kernel(const int* __restrict__ src,
                            const int* __restrict__ dst,
                            int* __restrict__ cursor,
                            int* __restrict__ csr_src) {
    const int e4 = blockIdx.x * 256 + threadIdx.x;
    if (e4 >= N_EDGES / 4) return;
    int4 s = *(const int4*)(src + e4 * 4);
    int4 d = *(const int4*)(dst + e4 * 4);
    csr_src[atomicAdd(&cursor[d.x], 1)] = s.x;
    csr_src[atomicAdd(&cursor[d.y], 1)] = s.y;
    csr_src[atomicAdd(&cursor[d.z], 1)] = s.z;
    csr_src[atomicAdd(&cursor[d.w], 1)] = s.w;
}

// ---------------------------------------------------------------------------
// Gather: one wave per node; c = l&7 (4 f16-pairs), g = l>>3 (8 neighbor
// groups). Row = 128B = one cacheline; v_pk_add_f16 accumulation (no unpack);
// packed shfl reduce; mean written as f16 row to meanf.
// ---------------------------------------------------------------------------
__global__ __launch_bounds__(256) void gather_kernel(
        const _Float16* __restrict__ xf,
        const int* __restrict__ rowptr,
        const int* __restrict__ csr_src,
        _Float16* __restrict__ meanf) {
    const int n = blockIdx.x * 4 + (threadIdx.x >> 6);
    const int l = threadIdx.x & 63;
    const int c = l & 7;
    const int g = l >> 3;

    const int beg = rowptr[n];
    const int end = rowptr[n + 1];
    const int deg = end - beg;
    const int chunk = (deg + 7) >> 3;

    H2U a0, a1, a2, a3;
    a0.u = a1.u = a2.u = a3.u = 0;
    {
        int i = beg + g * chunk;
        const int ce = min(i + chunk, end);
        for (; i + 1 < ce; i += 2) {
            const int p = csr_src[i];
            const int q = csr_src[i + 1];
            uint4 up = *(const uint4*)(xf + p * 64 + c * 8);
            uint4 uq = *(const uint4*)(xf + q * 64 + c * 8);
            H2U t;
            t.u = up.x; a0.h += t.h;  t.u = uq.x; a0.h += t.h;
            t.u = up.y; a1.h += t.h;  t.u = uq.y; a1.h += t.h;
            t.u = up.z; a2.h += t.h;  t.u = uq.z; a2.h += t.h;
            t.u = up.w; a3.h += t.h;  t.u = uq.w; a3.h += t.h;
        }
        if (i < ce) {
            const int p = csr_src[i];
            uint4 up = *(const uint4*)(xf + p * 64 + c * 8);
            H2U t;
            t.u = up.x; a0.h += t.h;
            t.u = up.y; a1.h += t.h;
            t.u = up.z; a2.h += t.h;
            t.u = up.w; a3.h += t.h;
        }
    }
    #pragma unroll
    for (int off = 8; off <= 32; off <<= 1) {
        H2U r;
        r.u = (unsigned)__shfl_xor((int)a0.u, off); a0.h += r.h;
        r.u = (unsigned)__shfl_xor((int)a1.u, off); a1.h += r.h;
        r.u = (unsigned)__shfl_xor((int)a2.u, off); a2.h += r.h;
        r.u = (unsigned)__shfl_xor((int)a3.u, off); a3.h += r.h;
    }
    const float rdeg = 1.0f / fmaxf((float)deg, 1.0f);
    const _Float16 rh = (_Float16)rdeg;
    const h2v rd2 = { rh, rh };
    a0.h *= rd2; a1.h *= rd2; a2.h *= rd2; a3.h *= rd2;
    if (g == 0) {
        uint4 o = { a0.u, a1.u, a2.u, a3.u };
        *(uint4*)(meanf + n * 64 + c * 8) = o;
    }
}

// ---------------------------------------------------------------------------
// MLP via MFMA: one wave = 16 nodes. A = [mean | x] (16x128 f16), B = packed
// [W1_l;W1_r] -> 16 mfma_f32_16x16x32_f16 -> h (+bias, relu). h round-trips
// LDS (stride 72 f16 = 144B, 16B-aligned, ~2-way banks) into A-layout, then
// [y2|z] = h @ [W2_l|W2_r] (4 MFMA). No cross-wave cooperation -> no barriers.
// C/D layout: col = lane&15, row = (lane>>4)*4 + reg (m89-verified).
// ---------------------------------------------------------------------------
__global__ __launch_bounds__(256) void mlp_kernel(
        const _Float16* __restrict__ xf,
        const _Float16* __restrict__ meanf,
        const _Float16* __restrict__ B1,
        const _Float16* __restrict__ B2,
        const float* __restrict__ b1,
        const float* __restrict__ b2,
        _Float16* __restrict__ y2f,
        float* __restrict__ z) {
    __shared__ _Float16 hlds[4][16 * 72];
    const int widx = threadIdx.x >> 6;
    const int l = threadIdx.x & 63;
    const int n0 = (blockIdx.x * 4 + widx) * 16;
    if (n0 >= N_NODES) return;                 // wave-uniform; no barriers used
    const int cn = l & 15;                     // A-row m / C-col n (in-tile)
    const int kq = l >> 4;                     // quad

    // A-fragments: kt 0..1 = mean (k 0..63), kt 2..3 = x (k 64..127)
    h8v af[4];
    const _Float16* mrow = meanf + (n0 + cn) * 64 + kq * 8;
    af[0] = *(const h8v*)(mrow);
    af[1] = *(const h8v*)(mrow + 32);
    const _Float16* xrow = xf + (n0 + cn) * 64 + kq * 8;
    af[2] = *(const h8v*)(xrow);
    af[3] = *(const h8v*)(xrow + 32);

    const f4v zero = { 0.f, 0.f, 0.f, 0.f };
    f4v acc[4] = { zero, zero, zero, zero };
    #pragma unroll
    for (int nt = 0; nt < 4; ++nt) {
        #pragma unroll
        for (int kt = 0; kt < 4; ++kt) {
            h8v bf = *(const h8v*)(B1 + ((kt * 4 + nt) * 64 + l) * 8);
            acc[nt] = __builtin_amdgcn_mfma_f32_16x16x32_f16(af[kt], bf, acc[nt], 0, 0, 0);
        }
    }

    // h = relu(acc + b1) -> LDS in A-layout (h_lds[m][k], stride 72)
    _Float16* hl = &hlds[widx][0];
    #pragma unroll
    for (int nt = 0; nt < 4; ++nt) {
        const float bias = b1[nt * 16 + cn];
        #pragma unroll
        for (int r = 0; r < 4; ++r) {
            const float hv = fmaxf(acc[nt][r] + bias, 0.f);
            hl[(kq * 4 + r) * 72 + nt * 16 + cn] = (_Float16)hv;
        }
    }

    // [y2 | z] = h @ [W2_l | W2_r]
    h8v a2[2];
    a2[0] = *(const h8v*)(hl + cn * 72 + kq * 8);
    a2[1] = *(const h8v*)(hl + cn * 72 + 32 + kq * 8);
    f4v acc2[2] = { zero, zero };
    #pragma unroll
    for (int nt = 0; nt < 2; ++nt) {
        #pragma unroll
        for (int kt = 0; kt < 2; ++kt) {
            h8v bf = *(const h8v*)(B2 + ((kt * 2 + nt) * 64 + l) * 8);
            acc2[nt] = __builtin_amdgcn_mfma_f32_16x16x32_f16(a2[kt], bf, acc2[nt], 0, 0, 0);
        }
    }
    const float bz = b2[cn];
    #pragma unroll
    for (int r = 0; r < 4; ++r) {
        const int row = n0 + kq * 4 + r;
        y2f[row * 16 + cn] = (_Float16)acc2[0][r];
        z[row * 16 + cn] = acc2[1][r] + bz;
    }
}

// ---------------------------------------------------------------------------
// Layer 2: gather-mean of f16 y2 (32B rows; c2 = t&1 feature half, p2 = t>>1
// neighbor slot; 4 nodes/wave) with packed-f16 accumulation, + z -> out.
// ---------------------------------------------------------------------------
__global__ __launch_bounds__(256) void layer2_kernel(
        const _Float16* __restrict__ y2f,
        const float* __restrict__ z,
        const int* __restrict__ rowptr,
        const int* __restrict__ csr_src,
        float* __restrict__ out) {
    const int wv = blockIdx.x * 4 + (threadIdx.x >> 6);
    const int l = threadIdx.x & 63;
    const int n = wv * 4 + (l >> 4);
    const int t = l & 15;
    const int c2 = t & 1;
    const int p2 = t >> 1;

    const int beg = rowptr[n];
    const int end = rowptr[n + 1];
    const int deg = end - beg;
    const int chunk = (deg + 7) >> 3;

    H2U a0, a1, a2, a3;
    a0.u = a1.u = a2.u = a3.u = 0;
    {
        int i = beg + p2 * chunk;
        const int ce = min(i + chunk, end);
        for (; i + 1 < ce; i += 2) {
            const int p = csr_src[i];
            const int q = csr_src[i + 1];
            uint4 up = *(const uint4*)(y2f + p * 16 + c2 * 8);
            uint4 uq = *(const uint4*)(y2f + q * 16 + c2 * 8);
            H2U r;
            r.u = up.x; a0.h += r.h;  r.u = uq.x; a0.h += r.h;
            r.u = up.y; a1.h += r.h;  r.u = uq.y; a1.h += r.h;
            r.u = up.z; a2.h += r.h;  r.u = uq.z; a2.h += r.h;
            r.u = up.w; a3.h += r.h;  r.u = uq.w; a3.h += r.h;
        }
        if (i < ce) {
            const int p = csr_src[i];
            uint4 up = *(const uint4*)(y2f + p * 16 + c2 * 8);
            H2U r;
            r.u = up.x; a0.h += r.h;
            r.u = up.y; a1.h += r.h;
            r.u = up.z; a2.h += r.h;
            r.u = up.w; a3.h += r.h;
        }
    }
    #pragma unroll
    for (int off = 2; off <= 8; off <<= 1) {
        H2U r;
        r.u = (unsigned)__shfl_xor((int)a0.u, off); a0.h += r.h;
        r.u = (unsigned)__shfl_xor((int)a1.u, off); a1.h += r.h;
        r.u = (unsigned)__shfl_xor((int)a2.u, off); a2.h += r.h;
        r.u = (unsigned)__shfl_xor((int)a3.u, off); a3.h += r.h;
    }
    if (p2 == 0) {
        const float rdeg = 1.0f / fmaxf((float)deg, 1.0f);
        const float4 z0 = *(const float4*)(z + n * 16 + c2 * 8);
        const float4 z1 = *(const float4*)(z + n * 16 + c2 * 8 + 4);
        float4 o0 = { (float)a0.h[0] * rdeg + z0.x, (float)a0.h[1] * rdeg + z0.y,
                      (float)a1.h[0] * rdeg + z0.z, (float)a1.h[1] * rdeg + z0.w };
        float4 o1 = { (float)a2.h[0] * rdeg + z1.x, (float)a2.h[1] * rdeg + z1.y,
                      (float)a3.h[0] * rdeg + z1.z, (float)a3.h[1] * rdeg + z1.w };
        *(float4*)(out + n * 16 + c2 * 8) = o0;
        *(float4*)(out + n * 16 + c2 * 8 + 4) = o1;
    }
}

extern "C" void kernel_launch(void* const* d_in, const int* in_sizes, int n_in,
                              void* d_out, int out_size, void* d_ws, size_t ws_size,
                              hipStream_t stream) {
    const float* x    = (const float*)d_in[0];
    const int*   ei   = (const int*)d_in[1];   // [2, 800000]: row 0 = src, row 1 = dst
    const float* W1_l = (const float*)d_in[2];
    const float* b1   = (const float*)d_in[3];
    const float* W1_r = (const float*)d_in[4];
    const float* W2_l = (const float*)d_in[5];
    const float* b2   = (const float*)d_in[6];
    const float* W2_r = (const float*)d_in[7];
    float* out = (float*)d_out;

    const int* src = ei;
    const int* dst = ei + N_EDGES;

    // Workspace layout (4-byte units):
    int* ws = (int*)d_ws;
    int*   cnt     = ws;                              // PAD_N
    int*   loc     = cnt     + PAD_N;                 // PAD_N
    int*   rowptr  = loc     + PAD_N;                 // PAD_N
    int*   cursor  = rowptr  + PAD_N;                 // PAD_N
    int*   bsum    = cursor  + PAD_N;                 // 64
    int*   csr_src = bsum    + 64;                    // 800,000
    _Float16* xf    = (_Float16*)(csr_src + 800000);  // 3,200,000 f16
    _Float16* meanf = xf + 3200000;                   // 3,200,000 f16
    _Float16* B1    = meanf + 3200000;                // 8,192 f16
    _Float16* B2    = B1 + 8192;                      // 2,048 f16
    _Float16* y2f   = B2 + 2048;                      // 800,000 f16
    float*    z     = (float*)(y2f + 800000);         // 800,000 f32
    // total ~21.6 MB

    hipMemsetAsync(cnt, 0, PAD_N * sizeof(int), stream);

    prep_kernel<<<3125, 256, 0, stream>>>(dst, x, W1_l, W1_r, W2_l, W2_r,
                                          cnt, xf, B1, B2);
    scanA_kernel<<<SCAN_BLOCKS, 256, 0, stream>>>(cnt, loc, bsum);
    scanC_kernel<<<SCAN_BLOCKS, 256, 0, stream>>>(loc, bsum, rowptr, cursor);
    fill_kernel<<<(N_EDGES / 4 + 255) / 256, 256, 0, stream>>>(src, dst, cursor, csr_src);
    gather_kernel<<<N_NODES / 4, 256, 0, stream>>>(xf, rowptr, csr_src, meanf);
    mlp_kernel<<<(N_NODES / 16 + 3) / 4, 256, 0, stream>>>(xf, meanf, B1, B2,
                                                           b1, b2, y2f, z);
    layer2_kernel<<<N_NODES / 16, 256, 0, stream>>>(y2f, z, rowptr, csr_src, out);
}